// Round 5
// baseline (61.048 us; speedup 1.0000x reference)
//
#include <hip/hip_runtime.h>

#define LN_EPS 1e-5f

// out[b,n,f,e] = LN(x[b,n,:])[f] * w[f,e] + (pb[f,e] + emb[f,e])
// B=4, N=4096, F=64, E=64 -> rows = 16384, 4096 fp32 outputs per row.
//
// R5: R4 (nt stores, no LDS/barrier, wave-redundant LN, joint butterfly)
// + 4 rows per block (4096 blocks): amortizes the 48 KiB table load 4x
// (L1/L2 read traffic 768 MB -> 192 MB), gives 4 independent interleaved
// LN butterfly chains (ILP over the ~30cyc cross-lane latency), and each
// block writes 64 KiB of consecutive output (DRAM page locality).

typedef float f4 __attribute__((ext_vector_type(4)));

#define ROWS_PER_BLOCK 4

__global__ __launch_bounds__(256) void pte_kernel(
    const float* __restrict__ x,      // [rows, 64]
    const float* __restrict__ gamma,  // [64]
    const float* __restrict__ beta,   // [64]
    const float* __restrict__ w,      // [64, 64]
    const float* __restrict__ pb,     // [64, 64]
    const float* __restrict__ emb,    // [64, 64]
    float* __restrict__ out)          // [rows, 4096]
{
    const int r0   = blockIdx.x * ROWS_PER_BLOCK;
    const int tid  = threadIdx.x;
    const int lane = tid & 63;

    // --- Issue x loads for all rows + table loads up front (independent) ---
    float v[ROWS_PER_BLOCK];
    #pragma unroll
    for (int j = 0; j < ROWS_PER_BLOCK; ++j)
        v[j] = x[(size_t)(r0 + j) * 64 + lane];

    const f4* __restrict__ w4 = (const f4*)w;
    const f4* __restrict__ b4 = (const f4*)pb;
    const f4* __restrict__ e4 = (const f4*)emb;

    f4 wv[4], cv[4];
    #pragma unroll
    for (int i = 0; i < 4; ++i) {
        int idx = i * 256 + tid;      // float4 index in [0,1024)
        wv[i] = w4[idx];
        f4 bv = b4[idx], ev = e4[idx];
        cv[i] = bv + ev;
    }

    const float g  = gamma[lane];
    const float bt = beta[lane];

    // --- 4 independent LN butterflies (interleaved by unroll) ---
    float s[ROWS_PER_BLOCK], s2[ROWS_PER_BLOCK];
    #pragma unroll
    for (int j = 0; j < ROWS_PER_BLOCK; ++j) {
        s[j]  = v[j];
        s2[j] = v[j] * v[j];
    }
    #pragma unroll
    for (int m = 1; m < 64; m <<= 1) {
        #pragma unroll
        for (int j = 0; j < ROWS_PER_BLOCK; ++j) {
            s[j]  += __shfl_xor(s[j],  m, 64);
            s2[j] += __shfl_xor(s2[j], m, 64);
        }
    }

    float xn_lane[ROWS_PER_BLOCK];
    #pragma unroll
    for (int j = 0; j < ROWS_PER_BLOCK; ++j) {
        float mu  = s[j] * (1.0f / 64.0f);
        float var = fmaf(-mu, mu, s2[j] * (1.0f / 64.0f));
        float inv = rsqrtf(var + LN_EPS);
        xn_lane[j] = (v[j] - mu) * inv * g + bt;
    }

    // f for this thread's i-th chunk: f = i*16 + (tid>>4); as a lane index
    // within this wave: i*16 + wave*4 + (lane>>4) == i*16 + fbase.
    const int fbase = ((tid >> 6) << 2) + (lane >> 4);

    // --- Emit 4 rows x 4096 floats as nontemporal float4 stores ---
    #pragma unroll
    for (int j = 0; j < ROWS_PER_BLOCK; ++j) {
        f4* __restrict__ o4 = (f4*)(out + (size_t)(r0 + j) * 4096);
        #pragma unroll
        for (int i = 0; i < 4; ++i) {
            float xn = __shfl(xn_lane[j], i * 16 + fbase, 64);
            f4 r;
            r.x = fmaf(xn, wv[i].x, cv[i].x);
            r.y = fmaf(xn, wv[i].y, cv[i].y);
            r.z = fmaf(xn, wv[i].z, cv[i].z);
            r.w = fmaf(xn, wv[i].w, cv[i].w);
            __builtin_nontemporal_store(r, &o4[i * 256 + tid]);
        }
    }
}

extern "C" void kernel_launch(void* const* d_in, const int* in_sizes, int n_in,
                              void* d_out, int out_size, void* d_ws, size_t ws_size,
                              hipStream_t stream) {
    const float* x     = (const float*)d_in[0];  // [4,4096,64]
    const float* gamma = (const float*)d_in[1];  // [64]
    const float* beta  = (const float*)d_in[2];  // [64]
    const float* w     = (const float*)d_in[3];  // [64,64]
    const float* pb    = (const float*)d_in[4];  // [64,64]
    const float* emb   = (const float*)d_in[5];  // [64,64]
    float* out = (float*)d_out;

    const int rows = 4 * 4096;                    // B * N
    const int grid = rows / ROWS_PER_BLOCK;       // 4096 blocks
    pte_kernel<<<grid, 256, 0, stream>>>(x, gamma, beta, w, pb, emb, out);
}

// Round 6
// 56.349 us; speedup vs baseline: 1.0834x; 1.0834x over previous
//
#include <hip/hip_runtime.h>

#define LN_EPS 1e-5f

// out[b,n,f,e] = LN(x[b,n,:])[f] * w[f,e] + (pb[f,e] + emb[f,e])
// B=4, N=4096, F=64, E=64 -> rows = 16384, 4096 fp32 outputs per row.
//
// R6: two-kernel split.
//  K1: xn[rows,64] -> ws (one wave per row, joint sum/sumsq butterfly);
//      block 0 also writes c = pb + emb (16 KiB) -> ws.
//  K2: pure stream, one row per block: per-thread 4x f4 of w and c
//      (32 KiB/block total -- fits 32 KiB L1 exactly, retained across
//      blocks), 4 broadcast xn scalars, fma, nontemporal f4 stores.
//      No shfl / no barrier / minimal VGPR in the hot kernel.

typedef float f4 __attribute__((ext_vector_type(4)));

__global__ __launch_bounds__(256) void pte_ln_kernel(
    const float* __restrict__ x,      // [rows, 64]
    const float* __restrict__ gamma,  // [64]
    const float* __restrict__ beta,   // [64]
    const float* __restrict__ pb,     // [64, 64]
    const float* __restrict__ emb,    // [64, 64]
    float* __restrict__ xn_ws,        // [rows, 64]
    float* __restrict__ c_ws)         // [64, 64]
{
    const int tid  = threadIdx.x;
    const int lane = tid & 63;
    const int wave = tid >> 6;
    const int row  = blockIdx.x * 4 + wave;

    // c = pb + emb, computed by block 0 (256 threads x 4 f4 = 4096 floats)
    if (blockIdx.x == 0) {
        const f4* __restrict__ b4 = (const f4*)pb;
        const f4* __restrict__ e4 = (const f4*)emb;
        f4* __restrict__ c4 = (f4*)c_ws;
        #pragma unroll
        for (int i = 0; i < 4; ++i) {
            int idx = i * 256 + tid;
            c4[idx] = b4[idx] + e4[idx];
        }
    }

    float v = x[(size_t)row * 64 + lane];
    float s = v, s2 = v * v;
    #pragma unroll
    for (int m = 1; m < 64; m <<= 1) {
        s  += __shfl_xor(s,  m, 64);
        s2 += __shfl_xor(s2, m, 64);
    }
    float mu  = s * (1.0f / 64.0f);
    float var = fmaf(-mu, mu, s2 * (1.0f / 64.0f));
    float inv = rsqrtf(var + LN_EPS);
    xn_ws[(size_t)row * 64 + lane] = (v - mu) * inv * gamma[lane] + beta[lane];
}

__global__ __launch_bounds__(256) void pte_emit_kernel(
    const float* __restrict__ xn_ws,  // [rows, 64]
    const float* __restrict__ w,      // [64, 64]
    const float* __restrict__ c_ws,   // [64, 64]
    float* __restrict__ out)          // [rows, 4096]
{
    const int row = blockIdx.x;
    const int tid = threadIdx.x;

    const f4* __restrict__ w4 = (const f4*)w;
    const f4* __restrict__ c4 = (const f4*)c_ws;
    const float* __restrict__ xr = xn_ws + (size_t)row * 64;
    f4* __restrict__ o4 = (f4*)(out + (size_t)row * 4096);

    // thread's i-th chunk covers feature f = i*16 + (tid>>4)
    const int f0 = tid >> 4;

    float xn[4];
    #pragma unroll
    for (int i = 0; i < 4; ++i) xn[i] = xr[i * 16 + f0];

    #pragma unroll
    for (int i = 0; i < 4; ++i) {
        int idx = i * 256 + tid;
        f4 wv = w4[idx];
        f4 cv = c4[idx];
        f4 r;
        r.x = fmaf(xn[i], wv.x, cv.x);
        r.y = fmaf(xn[i], wv.y, cv.y);
        r.z = fmaf(xn[i], wv.z, cv.z);
        r.w = fmaf(xn[i], wv.w, cv.w);
        __builtin_nontemporal_store(r, &o4[idx]);
    }
}

extern "C" void kernel_launch(void* const* d_in, const int* in_sizes, int n_in,
                              void* d_out, int out_size, void* d_ws, size_t ws_size,
                              hipStream_t stream) {
    const float* x     = (const float*)d_in[0];  // [4,4096,64]
    const float* gamma = (const float*)d_in[1];  // [64]
    const float* beta  = (const float*)d_in[2];  // [64]
    const float* w     = (const float*)d_in[3];  // [64,64]
    const float* pb    = (const float*)d_in[4];  // [64,64]
    const float* emb   = (const float*)d_in[5];  // [64,64]
    float* out = (float*)d_out;

    const int rows = 4 * 4096;  // B * N

    float* c_ws  = (float*)d_ws;                 // 4096 floats (16 KiB)
    float* xn_ws = (float*)d_ws + 4096;          // rows*64 floats (4 MiB)

    pte_ln_kernel<<<rows / 4, 256, 0, stream>>>(x, gamma, beta, pb, emb,
                                                xn_ws, c_ws);
    pte_emit_kernel<<<rows, 256, 0, stream>>>(xn_ws, w, c_ws, out);
}

// Round 7
// 54.074 us; speedup vs baseline: 1.1290x; 1.0421x over previous
//
#include <hip/hip_runtime.h>

#define LN_EPS 1e-5f

// out[b,n,f,e] = LN(x[b,n,:])[f] * w[f,e] + (pb[f,e] + emb[f,e])
// B=4, N=4096, F=64, E=64 -> rows = 16384, 4096 fp32 outputs per row.
//
// R7: R4 hot kernel unchanged in structure; only the per-block read set
// shrinks from 48 KiB (w, pb, emb) to 32 KiB (w, c=pb+emb) via a 1-block
// prelude writing c into d_ws. 32 KiB exactly fits per-CU L1 (stores are
// no-allocate), so tables stay L1-resident across the ~64 blocks/CU.

typedef float f4 __attribute__((ext_vector_type(4)));

__global__ __launch_bounds__(256) void pte_prelude_kernel(
    const float* __restrict__ pb,     // [64, 64]
    const float* __restrict__ emb,    // [64, 64]
    float* __restrict__ c_ws)         // [64, 64]
{
    const int tid = threadIdx.x;
    const f4* __restrict__ b4 = (const f4*)pb;
    const f4* __restrict__ e4 = (const f4*)emb;
    f4* __restrict__ c4 = (f4*)c_ws;
    #pragma unroll
    for (int i = 0; i < 4; ++i) {
        int idx = i * 256 + tid;
        c4[idx] = b4[idx] + e4[idx];
    }
}

__global__ __launch_bounds__(256) void pte_kernel(
    const float* __restrict__ x,      // [rows, 64]
    const float* __restrict__ gamma,  // [64]
    const float* __restrict__ beta,   // [64]
    const float* __restrict__ w,      // [64, 64]
    const float* __restrict__ c_ws,   // [64, 64] = pb + emb
    float* __restrict__ out)          // [rows, 4096]
{
    const int row  = blockIdx.x;
    const int tid  = threadIdx.x;
    const int lane = tid & 63;

    // --- Issue table loads first (independent of LN) ---
    const f4* __restrict__ w4 = (const f4*)w;
    const f4* __restrict__ c4 = (const f4*)c_ws;

    f4 wv[4], cv[4];
    #pragma unroll
    for (int i = 0; i < 4; ++i) {
        int idx = i * 256 + tid;      // float4 index in [0,1024)
        wv[i] = w4[idx];
        cv[i] = c4[idx];
    }

    // --- LayerNorm (wave-redundant, joint sum/sumsq butterfly) ---
    float v  = x[(size_t)row * 64 + lane];
    float g  = gamma[lane];
    float bt = beta[lane];

    float s  = v;
    float s2 = v * v;
    #pragma unroll
    for (int m = 1; m < 64; m <<= 1) {
        s  += __shfl_xor(s,  m, 64);
        s2 += __shfl_xor(s2, m, 64);
    }
    float mu  = s * (1.0f / 64.0f);
    float var = fmaf(-mu, mu, s2 * (1.0f / 64.0f));
    float inv = rsqrtf(var + LN_EPS);
    float xn_lane = (v - mu) * inv * g + bt;

    // f for this thread's i-th chunk: f = i*16 + (tid>>4); as a lane index
    // within this wave: i*16 + wave*4 + (lane>>4) == i*16 + fbase.
    const int fbase = ((tid >> 6) << 2) + (lane >> 4);

    // --- Emit 4096 floats as 1024 nontemporal float4 stores (4 / thread) ---
    f4* __restrict__ o4 = (f4*)(out + (size_t)row * 4096);
    #pragma unroll
    for (int i = 0; i < 4; ++i) {
        float xn = __shfl(xn_lane, i * 16 + fbase, 64);
        f4 r;
        r.x = fmaf(xn, wv[i].x, cv[i].x);
        r.y = fmaf(xn, wv[i].y, cv[i].y);
        r.z = fmaf(xn, wv[i].z, cv[i].z);
        r.w = fmaf(xn, wv[i].w, cv[i].w);
        __builtin_nontemporal_store(r, &o4[i * 256 + tid]);
    }
}

extern "C" void kernel_launch(void* const* d_in, const int* in_sizes, int n_in,
                              void* d_out, int out_size, void* d_ws, size_t ws_size,
                              hipStream_t stream) {
    const float* x     = (const float*)d_in[0];  // [4,4096,64]
    const float* gamma = (const float*)d_in[1];  // [64]
    const float* beta  = (const float*)d_in[2];  // [64]
    const float* w     = (const float*)d_in[3];  // [64,64]
    const float* pb    = (const float*)d_in[4];  // [64,64]
    const float* emb   = (const float*)d_in[5];  // [64,64]
    float* out = (float*)d_out;

    float* c_ws = (float*)d_ws;  // 4096 floats (16 KiB)

    const int rows = 4 * 4096;  // B * N
    pte_prelude_kernel<<<1, 256, 0, stream>>>(pb, emb, c_ws);
    pte_kernel<<<rows, 256, 0, stream>>>(x, gamma, beta, w, c_ws, out);
}

// Round 8
// 47.680 us; speedup vs baseline: 1.2804x; 1.1341x over previous
//
#include <hip/hip_runtime.h>

#define LN_EPS 1e-5f

// out[b,n,f,e] = LN(x[b,n,:])[f] * w[f,e] + (pb[f,e] + emb[f,e])
// B=4, N=4096, F=64, E=64 -> rows = 16384, 4096 fp32 outputs per row.
//
// R8 = R4 (best: 51.1 us) with the critical-path x load issued first.
// Design notes (validated over R0-R7):
//  - one row per block, 16384 short-lived blocks (persistent/multi-row/split
//    variants all measured worse: 57.6 / 61.0 / 56.3 vs 51.1).
//  - table re-fetch per block is NOT a limiter (3 falsifications).
//  - no LDS / no __syncthreads: wave-redundant LN + __shfl broadcast.
//  - joint sum/sumsq butterfly: 6 dependent cross-lane steps.
//  - nontemporal f4 stores (+6% vs plain): output is write-once.

typedef float f4 __attribute__((ext_vector_type(4)));

__global__ __launch_bounds__(256) void pte_kernel(
    const float* __restrict__ x,      // [rows, 64]
    const float* __restrict__ gamma,  // [64]
    const float* __restrict__ beta,   // [64]
    const float* __restrict__ w,      // [64, 64]
    const float* __restrict__ pb,     // [64, 64]
    const float* __restrict__ emb,    // [64, 64]
    float* __restrict__ out)          // [rows, 4096]
{
    const int row  = blockIdx.x;
    const int tid  = threadIdx.x;
    const int lane = tid & 63;

    // --- Critical-path load first: x row (HBM miss ~900 cyc) ---
    float v  = x[(size_t)row * 64 + lane];
    float g  = gamma[lane];
    float bt = beta[lane];

    // --- Table loads (latency-tolerant, overlap the LN reduction) ---
    const f4* __restrict__ w4 = (const f4*)w;
    const f4* __restrict__ b4 = (const f4*)pb;
    const f4* __restrict__ e4 = (const f4*)emb;

    f4 wv[4], bv[4], ev[4];
    #pragma unroll
    for (int i = 0; i < 4; ++i) {
        int idx = i * 256 + tid;      // float4 index in [0,1024)
        wv[i] = w4[idx];
        bv[i] = b4[idx];
        ev[i] = e4[idx];
    }

    // --- LayerNorm (wave-redundant, joint sum/sumsq butterfly) ---
    float s  = v;
    float s2 = v * v;
    #pragma unroll
    for (int m = 1; m < 64; m <<= 1) {
        s  += __shfl_xor(s,  m, 64);
        s2 += __shfl_xor(s2, m, 64);
    }
    float mu  = s * (1.0f / 64.0f);
    float var = fmaf(-mu, mu, s2 * (1.0f / 64.0f));
    float inv = rsqrtf(var + LN_EPS);
    float xn_lane = (v - mu) * inv * g + bt;

    // f for this thread's i-th chunk: f = i*16 + (tid>>4); as a lane index
    // within this wave: i*16 + wave*4 + (lane>>4) == i*16 + fbase.
    const int fbase = ((tid >> 6) << 2) + (lane >> 4);

    // --- Emit 4096 floats as 1024 nontemporal float4 stores (4 / thread) ---
    f4* __restrict__ o4 = (f4*)(out + (size_t)row * 4096);
    #pragma unroll
    for (int i = 0; i < 4; ++i) {
        float xn = __shfl(xn_lane, i * 16 + fbase, 64);
        f4 r;
        r.x = fmaf(xn, wv[i].x, bv[i].x + ev[i].x);
        r.y = fmaf(xn, wv[i].y, bv[i].y + ev[i].y);
        r.z = fmaf(xn, wv[i].z, bv[i].z + ev[i].z);
        r.w = fmaf(xn, wv[i].w, bv[i].w + ev[i].w);
        __builtin_nontemporal_store(r, &o4[i * 256 + tid]);
    }
}

extern "C" void kernel_launch(void* const* d_in, const int* in_sizes, int n_in,
                              void* d_out, int out_size, void* d_ws, size_t ws_size,
                              hipStream_t stream) {
    const float* x     = (const float*)d_in[0];  // [4,4096,64]
    const float* gamma = (const float*)d_in[1];  // [64]
    const float* beta  = (const float*)d_in[2];  // [64]
    const float* w     = (const float*)d_in[3];  // [64,64]
    const float* pb    = (const float*)d_in[4];  // [64,64]
    const float* emb   = (const float*)d_in[5];  // [64,64]
    float* out = (float*)d_out;

    const int rows = 4 * 4096;  // B * N
    pte_kernel<<<rows, 256, 0, stream>>>(x, gamma, beta, w, pb, emb, out);
}